// Round 9
// baseline (39.093 us; speedup 1.0000x reference)
//
#include <hip/hip_runtime.h>
#include <stdint.h>

#define B_ 16
#define L_ 256
#define D_ 1024
#define R_ 128
#define M_ (B_*L_)   // 4096 rows of t

typedef short short8 __attribute__((ext_vector_type(8)));
typedef float f32x4 __attribute__((ext_vector_type(4)));

__device__ __forceinline__ unsigned short f2bf(float f) {
  union { float f; unsigned int u; } v; v.f = f;
  unsigned int r = v.u + 0x7FFFu + ((v.u >> 16) & 1u);  // RNE
  return (unsigned short)(r >> 16);
}
__device__ __forceinline__ float bf2f(unsigned short s) {
  union { unsigned int u; float f; } v; v.u = ((unsigned int)s) << 16;
  return v.f;
}

// ---------------- K0: P [1024][128] f32 -> PbT [128][1024] bf16 ----------------
__global__ __launch_bounds__(256) void k0_transpose_cast(
    const float* __restrict__ P, unsigned short* __restrict__ PbT) {
  int id = blockIdx.x * 256 + threadIdx.x;   // 0..16383
  int n  = id & 127;                         // consecutive across lanes
  int kc = id >> 7;                          // chunk of 8 k
  union { unsigned short s[8]; uint4 v; } u;
#pragma unroll
  for (int j = 0; j < 8; ++j) u.s[j] = f2bf(P[(kc * 8 + j) * R_ + n]);
  *reinterpret_cast<uint4*>(&PbT[(size_t)n * D_ + kc * 8]) = u.v;
}

// ---------------- K1: t = X @ P  (bf16 MFMA), direct-from-cache, no LDS tiles --
// BM=16, BN=64. grid=512. Barrier-free main loop: A-frags loaded straight from
// X (f32, 2 dwordx4 + 4 cvt_pk), B-frags straight from PbT (1 dwordx4, L2-hot).
// Epilogue: write bf16 T + per-col-half row norms (from the ROUNDED values)
// into Nrm2[half][m]  (two halves summed by K2; no atomics needed).
__global__ __launch_bounds__(256, 4) void k1_gemm(
    const float* __restrict__ X, const unsigned short* __restrict__ PbT,
    unsigned short* __restrict__ Tb, float* __restrict__ Nrm2) {
  __shared__ float nacc[16][4];

  const int tid  = threadIdx.x;
  const int lane = tid & 63;
  const int w    = tid >> 6;          // wave 0..3
  // XCD-bijective swizzle (512 % 8 == 0)
  const int lb   = (blockIdx.x & 7) * 64 + (blockIdx.x >> 3);
  const int m0   = (lb >> 1) * 16;
  const int nb0  = (lb & 1) * 64;

  const int ar = lane & 15;           // A row / B col within 16
  const int ko = (lane >> 4) * 8;     // k-octet offset within 32-k slice

  const float*          xrow = X   + (size_t)(m0 + ar) * D_;
  const unsigned short* prow = PbT + (size_t)(nb0 + w * 16 + ar) * D_;

  f32x4 acc;
  acc[0] = 0.f; acc[1] = 0.f; acc[2] = 0.f; acc[3] = 0.f;

#pragma unroll 2
  for (int kt = 0; kt < 8; ++kt) {
#pragma unroll
    for (int s = 0; s < 4; ++s) {
      const int k = kt * 128 + s * 32 + ko;
      float4 xa = *reinterpret_cast<const float4*>(xrow + k);
      float4 xb = *reinterpret_cast<const float4*>(xrow + k + 4);
      union { unsigned int u[4]; short8 s8; } cvt;
      asm("v_cvt_pk_bf16_f32 %0, %1, %2" : "=v"(cvt.u[0]) : "v"(xa.x), "v"(xa.y));
      asm("v_cvt_pk_bf16_f32 %0, %1, %2" : "=v"(cvt.u[1]) : "v"(xa.z), "v"(xa.w));
      asm("v_cvt_pk_bf16_f32 %0, %1, %2" : "=v"(cvt.u[2]) : "v"(xb.x), "v"(xb.y));
      asm("v_cvt_pk_bf16_f32 %0, %1, %2" : "=v"(cvt.u[3]) : "v"(xb.z), "v"(xb.w));
      short8 b = *reinterpret_cast<const short8*>(prow + k);
      acc = __builtin_amdgcn_mfma_f32_16x16x32_bf16(cvt.s8, b, acc, 0, 0, 0);
    }
  }

  // epilogue: write rounded T; accumulate half-norms of the ROUNDED values
  const int col = lane & 15;
#pragma unroll
  for (int q = 0; q < 4; ++q) {
    const int row = ((lane >> 4) << 2) + q;
    unsigned short hv = f2bf(acc[q]);
    Tb[(size_t)(m0 + row) * R_ + nb0 + w * 16 + col] = hv;
    float tr = bf2f(hv);
    float s = tr * tr;                 // sum over this wave's 16 cols
    s += __shfl_xor(s, 1); s += __shfl_xor(s, 2);
    s += __shfl_xor(s, 4); s += __shfl_xor(s, 8);
    if (col == 0) nacc[row][w] = s;
  }
  __syncthreads();
  if (tid < 16) {
    float t = nacc[tid][0] + nacc[tid][1] + nacc[tid][2] + nacc[tid][3];
    Nrm2[(size_t)(lb & 1) * M_ + m0 + tid] = t;   // half-norm for cols [nb0,nb0+64)
  }
}

// ---------------- K2: per-batch Gram + distance epilogue, direct-from-cache ----
// block = (b, i-tile it, j-quarter jq). grid=1024. No LDS, no barriers:
// A/B fragments loaded straight from Tb (L2-hot, 1 dwordx4 each).
__global__ __launch_bounds__(256, 4) void k2_gram(
    const unsigned short* __restrict__ Tb, const float* __restrict__ Nrm2,
    float* __restrict__ Out) {
  const int tid  = threadIdx.x;
  const int lane = tid & 63;
  const int w    = tid >> 6;        // 0..3
  const int blk  = blockIdx.x;
  const int b    = blk >> 6;
  const int it   = (blk >> 2) & 15;
  const int jq   = blk & 3;

  const int ar = lane & 15;
  const int ko = (lane >> 4) * 8;

  const unsigned short* irow = Tb + (size_t)(b * L_ + it * 16 + ar) * R_;
  const unsigned short* jrow = Tb + (size_t)(b * L_ + jq * 64 + w * 16 + ar) * R_;

  f32x4 acc;
  acc[0] = 0.f; acc[1] = 0.f; acc[2] = 0.f; acc[3] = 0.f;
#pragma unroll
  for (int s = 0; s < 4; ++s) {
    short8 a  = *reinterpret_cast<const short8*>(irow + s * 32 + ko);
    short8 bv = *reinterpret_cast<const short8*>(jrow + s * 32 + ko);
    acc = __builtin_amdgcn_mfma_f32_16x16x32_bf16(a, bv, acc, 0, 0, 0);
  }

  const int col = lane & 15;
  const int jj  = jq * 64 + w * 16 + col;
  const float nj = Nrm2[b * L_ + jj] + Nrm2[M_ + b * L_ + jj];
#pragma unroll
  for (int q = 0; q < 4; ++q) {
    const int ir = it * 16 + ((lane >> 4) << 2) + q;
    const float ni = Nrm2[b * L_ + ir] + Nrm2[M_ + b * L_ + ir];
    float v = ni + nj - 2.0f * acc[q];
    Out[(size_t)(b * L_ + ir) * L_ + jj] = fmaxf(v, 0.0f);
  }
}

extern "C" void kernel_launch(void* const* d_in, const int* in_sizes, int n_in,
                              void* d_out, int out_size, void* d_ws, size_t ws_size,
                              hipStream_t stream) {
  const float* X = (const float*)d_in[0];   // [16,256,1024]
  const float* P = (const float*)d_in[1];   // [1024,128]
  float* Out = (float*)d_out;               // [16,256,256]
  char* ws = (char*)d_ws;
  unsigned short* PbT = (unsigned short*)ws;                               // 256 KB
  unsigned short* Tb  = (unsigned short*)(ws + (size_t)R_ * D_ * 2);       // 1 MB
  float* Nrm2 = (float*)(ws + (size_t)R_ * D_ * 2 + (size_t)M_ * R_ * 2);  // 32 KB

  k0_transpose_cast<<<64, 256, 0, stream>>>(P, PbT);
  k1_gemm<<<512, 256, 0, stream>>>(X, PbT, Tb, Nrm2);
  k2_gram<<<1024, 256, 0, stream>>>(Tb, Nrm2, Out);
}

// Round 11
// 21.079 us; speedup vs baseline: 1.8546x; 1.8546x over previous
//
#include <hip/hip_runtime.h>
#include <stdint.h>

#define B_ 16
#define L_ 256
#define D_ 1024
#define R_ 128
#define M_ (B_*L_)   // 4096 rows of t

typedef short short8 __attribute__((ext_vector_type(8)));
typedef float f32x4 __attribute__((ext_vector_type(4)));

__device__ __forceinline__ unsigned short f2bf(float f) {
  union { float f; unsigned int u; } v; v.f = f;
  unsigned int r = v.u + 0x7FFFu + ((v.u >> 16) & 1u);  // RNE
  return (unsigned short)(r >> 16);
}
__device__ __forceinline__ float bf2f(unsigned short s) {
  union { unsigned int u; float f; } v; v.u = ((unsigned int)s) << 16;
  return v.f;
}
__device__ __forceinline__ void gload_lds16(const void* g, void* l) {
  __builtin_amdgcn_global_load_lds(
      (const __attribute__((address_space(1))) unsigned int*)g,
      (__attribute__((address_space(3))) unsigned int*)l, 16, 0, 0);
}

// ---------------- K0: P [1024][128] f32 -> PbT [128][1024] bf16 ----------------
__global__ __launch_bounds__(256) void k0_transpose_cast(
    const float* __restrict__ P, unsigned short* __restrict__ PbT) {
  int id = blockIdx.x * 256 + threadIdx.x;   // 0..16383
  int n  = id & 127;                         // consecutive across lanes
  int kc = id >> 7;                          // chunk of 8 k
  union { unsigned short s[8]; uint4 v; } u;
#pragma unroll
  for (int j = 0; j < 8; ++j) u.s[j] = f2bf(P[(kc * 8 + j) * R_ + n]);
  *reinterpret_cast<uint4*>(&PbT[(size_t)n * D_ + kc * 8]) = u.v;
}

// ---------------- K1: t = X @ P  (bf16 MFMA) + half-norms ----------------
// BM=16, BN=64, BK=128. grid=512, 2 blocks/CU. (Proven R7 structure; LDS 40KB.)
// Counted-vmcnt pipeline, race-free placement: ALL staging into buf^1 happens
// AFTER barrier@kt. Per-iter: waitcnt(vmcnt 2, lgkm 0) -> barrier -> compute(buf)
//                 -> issueP(buf^1) -> loadX(kt+2) -> writeX(buf^1).
// Epilogue: write bf16 T + this col-half's row norms (of the ROUNDED values)
// into Nrm2[half][m] — no atomics; K2 sums the two halves.
__global__ __launch_bounds__(256) void k1_gemm(
    const float* __restrict__ X, const unsigned short* __restrict__ PbT,
    unsigned short* __restrict__ Tb, float* __restrict__ Nrm2) {
  __shared__ unsigned short sX[2][16 * 128];    // 2 x 4KB, swizzled 256B rows
  __shared__ unsigned short sP[2][64 * 128];    // 2 x 16KB, swizzled 256B rows
  __shared__ float nacc[16][4];

  const int tid  = threadIdx.x;
  const int lane = tid & 63;
  const int w    = tid >> 6;          // wave 0..3
  // XCD-bijective swizzle (512 % 8 == 0)
  const int lb   = (blockIdx.x & 7) * 64 + (blockIdx.x >> 3);
  const int m0   = (lb >> 1) * 16;
  const int nb0  = (lb & 1) * 64;

  f32x4 acc;
  acc[0] = 0.f; acc[1] = 0.f; acc[2] = 0.f; acc[3] = 0.f;

  float4 xs[2][2];   // 2 prefetch slots x 2 chunks (statically indexed under unroll)

  auto loadX = [&](float4* slot, int kt) {
#pragma unroll
    for (int i = 0; i < 2; ++i) {
      int c = tid + 256 * i;
      int row = c >> 5, kq = (c & 31) * 4;
      slot[i] = *reinterpret_cast<const float4*>(&X[(size_t)(m0 + row) * D_ + kt * 128 + kq]);
    }
  };
  auto writeX = [&](int buf, const float4* slot) {
#pragma unroll
    for (int i = 0; i < 2; ++i) {
      int c = tid + 256 * i;
      int row = c >> 5, kq = (c & 31) * 4;
      uint2 p;
      p.x = (unsigned int)f2bf(slot[i].x) | ((unsigned int)f2bf(slot[i].y) << 16);
      p.y = (unsigned int)f2bf(slot[i].z) | ((unsigned int)f2bf(slot[i].w) << 16);
      int byte_in_row = (kq * 2) ^ ((row & 7) << 4);
      *reinterpret_cast<uint2*>(reinterpret_cast<char*>(&sX[buf][0]) + row * 256 + byte_in_row) = p;
    }
  };
  auto issueP = [&](int buf, int kt) {
    const int k0 = kt * 128;
#pragma unroll
    for (int i = 0; i < 4; ++i) {
      int c = tid + 256 * i;
      int row = c >> 4, ch = c & 15;   // 16 chunks per 256B row
      gload_lds16(&PbT[(size_t)(nb0 + row) * D_ + k0 + ((ch ^ (row & 7)) * 8)],
                  reinterpret_cast<char*>(&sP[buf][0]) + c * 16);
    }
  };
  auto compute = [&](int buf) {
    const char* xb = reinterpret_cast<const char*>(&sX[buf][0]);
    const char* pb = reinterpret_cast<const char*>(&sP[buf][0]);
#pragma unroll
    for (int s = 0; s < 4; ++s) {
      int koffb = s * 64 + ((lane >> 4) << 4);
      int ar = lane & 15;
      short8 a = *reinterpret_cast<const short8*>(xb + ar * 256 + (koffb ^ ((ar & 7) << 4)));
      int br = w * 16 + (lane & 15);
      short8 b = *reinterpret_cast<const short8*>(pb + br * 256 + (koffb ^ ((br & 7) << 4)));
      acc = __builtin_amdgcn_mfma_f32_16x16x32_bf16(a, b, acc, 0, 0, 0);
    }
  };

  // prologue: issue X(0), P(0), X(1); write sX[0] (compiler counted-waits X(0) only)
  loadX(xs[0], 0);
  issueP(0, 0);
  loadX(xs[1], 1);
  writeX(0, xs[0]);
  // outstanding: P(0)x4, X(1)x2

#pragma unroll
  for (int kt = 0; kt < 8; ++kt) {
    const int buf = kt & 1;
    // retire P(kt) (4 oldest); keep X loads in flight; publish last iter's sX writes
    if (kt == 7) asm volatile("s_waitcnt vmcnt(0) lgkmcnt(0)" ::: "memory");
    else         asm volatile("s_waitcnt vmcnt(2) lgkmcnt(0)" ::: "memory");
    __builtin_amdgcn_sched_barrier(0);
    __builtin_amdgcn_s_barrier();
    compute(buf);
    // staging into buf^1: safe, all waves passed barrier@kt (readers of buf^1 done)
    if (kt < 7) issueP(buf ^ 1, kt + 1);
    if (kt < 6) loadX(xs[kt & 1], kt + 2);
    if (kt < 7) writeX(buf ^ 1, xs[(kt + 1) & 1]);
  }

  // epilogue: write bf16 t; accumulate this col-half's norms of the ROUNDED values
  const int col = lane & 15;
#pragma unroll
  for (int q = 0; q < 4; ++q) {
    int row = ((lane >> 4) << 2) + q;
    unsigned short hv = f2bf(acc[q]);
    Tb[(size_t)(m0 + row) * R_ + nb0 + w * 16 + col] = hv;
    float tr = bf2f(hv);
    float s = tr * tr;                 // reduce over this wave's 16 cols
    s += __shfl_xor(s, 1); s += __shfl_xor(s, 2);
    s += __shfl_xor(s, 4); s += __shfl_xor(s, 8);
    if (col == 0) nacc[row][w] = s;
  }
  __syncthreads();
  if (tid < 16) {
    float t = nacc[tid][0] + nacc[tid][1] + nacc[tid][2] + nacc[tid][3];
    Nrm2[(size_t)(lb & 1) * M_ + m0 + tid] = t;   // half-norm for cols [nb0,nb0+64)
  }
}

// ---------------- K2: per-batch Gram + distance epilogue ----------------
// block = (b, i-tile it, j-quarter jq). grid=1024 -> 4 blocks/CU.
// Norms read from Nrm2 (L2-hot) — no serial norm section, no extra barrier.
__global__ __launch_bounds__(256) void k2_gram(
    const unsigned short* __restrict__ Tb, const float* __restrict__ Nrm2,
    float* __restrict__ Out) {
  __shared__ unsigned short sI[16 * 128];    // 4KB, swizzled 256B rows
  __shared__ unsigned short sJ[64 * 128];    // 16KB

  const int tid  = threadIdx.x;
  const int lane = tid & 63;
  const int w    = tid >> 6;        // 0..3
  const int blk  = blockIdx.x;
  const int b    = blk >> 6;
  const int it   = (blk >> 2) & 15;
  const int jq   = blk & 3;

  // stage sI: 256 chunks of 16B (1/thread)
  {
    int row = tid >> 4, ch = tid & 15;
    gload_lds16(&Tb[(size_t)(b * L_ + it * 16 + row) * R_ + ((ch ^ (row & 7)) * 8)],
                reinterpret_cast<char*>(sI) + tid * 16);
  }
  // stage sJ: 1024 chunks (4/thread)
#pragma unroll
  for (int i = 0; i < 4; ++i) {
    int c = tid + 256 * i;
    int row = c >> 4, ch = c & 15;
    gload_lds16(&Tb[(size_t)(b * L_ + jq * 64 + row) * R_ + ((ch ^ (row & 7)) * 8)],
                reinterpret_cast<char*>(sJ) + c * 16);
  }
  __syncthreads();

  // Gram via MFMA
  f32x4 acc;
  acc[0] = 0.f; acc[1] = 0.f; acc[2] = 0.f; acc[3] = 0.f;
  const char* ib = reinterpret_cast<const char*>(sI);
  const char* jb = reinterpret_cast<const char*>(sJ);
#pragma unroll
  for (int s = 0; s < 4; ++s) {
    int koffb = s * 64 + ((lane >> 4) << 4);
    int ar = lane & 15;
    short8 a = *reinterpret_cast<const short8*>(ib + ar * 256 + (koffb ^ ((ar & 7) << 4)));
    int br = w * 16 + (lane & 15);
    short8 bv = *reinterpret_cast<const short8*>(jb + br * 256 + (koffb ^ ((br & 7) << 4)));
    acc = __builtin_amdgcn_mfma_f32_16x16x32_bf16(a, bv, acc, 0, 0, 0);
  }

  const int col = lane & 15;
  const int jj  = jq * 64 + w * 16 + col;
  const float nj = Nrm2[b * L_ + jj] + Nrm2[M_ + b * L_ + jj];
  const int irb = it * 16 + ((lane >> 4) << 2);   // 4-aligned row base
  float4 niA = *reinterpret_cast<const float4*>(&Nrm2[b * L_ + irb]);
  float4 niB = *reinterpret_cast<const float4*>(&Nrm2[M_ + b * L_ + irb]);
#pragma unroll
  for (int q = 0; q < 4; ++q) {
    float ni = (q == 0 ? niA.x + niB.x : q == 1 ? niA.y + niB.y
              : q == 2 ? niA.z + niB.z : niA.w + niB.w);
    float v = ni + nj - 2.0f * acc[q];
    Out[(size_t)(b * L_ + irb + q) * L_ + jj] = fmaxf(v, 0.0f);
  }
}

extern "C" void kernel_launch(void* const* d_in, const int* in_sizes, int n_in,
                              void* d_out, int out_size, void* d_ws, size_t ws_size,
                              hipStream_t stream) {
  const float* X = (const float*)d_in[0];   // [16,256,1024]
  const float* P = (const float*)d_in[1];   // [1024,128]
  float* Out = (float*)d_out;               // [16,256,256]
  char* ws = (char*)d_ws;
  unsigned short* PbT = (unsigned short*)ws;                               // 256 KB
  unsigned short* Tb  = (unsigned short*)(ws + (size_t)R_ * D_ * 2);       // 1 MB
  float* Nrm2 = (float*)(ws + (size_t)R_ * D_ * 2 + (size_t)M_ * R_ * 2);  // 32 KB

  k0_transpose_cast<<<64, 256, 0, stream>>>(P, PbT);
  k1_gemm<<<M_ / 16 * 2, 256, 0, stream>>>(X, PbT, Tb, Nrm2);
  k2_gram<<<B_ * 16 * 4, 256, 0, stream>>>(Tb, Nrm2, Out);
}

// Round 12
// 20.738 us; speedup vs baseline: 1.8851x; 1.0164x over previous
//
#include <hip/hip_runtime.h>
#include <stdint.h>

#define B_ 16
#define L_ 256
#define D_ 1024
#define R_ 128
#define M_ (B_*L_)   // 4096 rows of t

typedef short short8 __attribute__((ext_vector_type(8)));
typedef float f32x4 __attribute__((ext_vector_type(4)));

__device__ __forceinline__ unsigned short f2bf(float f) {
  union { float f; unsigned int u; } v; v.f = f;
  unsigned int r = v.u + 0x7FFFu + ((v.u >> 16) & 1u);  // RNE
  return (unsigned short)(r >> 16);
}
__device__ __forceinline__ float bf2f(unsigned short s) {
  union { unsigned int u; float f; } v; v.u = ((unsigned int)s) << 16;
  return v.f;
}
__device__ __forceinline__ void gload_lds16(const void* g, void* l) {
  __builtin_amdgcn_global_load_lds(
      (const __attribute__((address_space(1))) unsigned int*)g,
      (__attribute__((address_space(3))) unsigned int*)l, 16, 0, 0);
}

// ---------------- K0: P [1024][128] f32 -> PbT [128][1024] bf16 ----------------
// 128 blocks (vs 64): each thread does a k-QUAD (4 strided loads + 8B store)
// -> half the latency chain, 2x CU coverage. Reads coalesced over n.
__global__ __launch_bounds__(256) void k0_transpose_cast(
    const float* __restrict__ P, unsigned short* __restrict__ PbT) {
  int id = blockIdx.x * 256 + threadIdx.x;   // 0..32767
  int n  = id & 127;                         // consecutive across lanes
  int kq = id >> 7;                          // quad of k: 0..255
  union { unsigned short s[4]; uint2 v; } u;
#pragma unroll
  for (int j = 0; j < 4; ++j) u.s[j] = f2bf(P[(kq * 4 + j) * R_ + n]);
  *reinterpret_cast<uint2*>(&PbT[(size_t)n * D_ + kq * 4]) = u.v;
}

// ---------------- K1: t = X @ P  (bf16 MFMA) ----------------
// BM=16, BN=64, BK=128. grid=512, 2 blocks/CU.  (R7 structure, verbatim.)
// Counted-vmcnt pipeline, race-free placement: ALL staging into buf^1 happens
// AFTER barrier@kt. Per-iter: waitcnt(vmcnt 2, lgkm 0) -> barrier -> compute(buf)
//                 -> issueP(buf^1) -> loadX(kt+2) -> writeX(buf^1).
__global__ __launch_bounds__(256) void k1_gemm(
    const float* __restrict__ X, const unsigned short* __restrict__ PbT,
    unsigned short* __restrict__ Tb) {
  __shared__ unsigned short sX[2][16 * 128];    // 2 x 4KB, swizzled 256B rows
  __shared__ unsigned short sP[2][64 * 128];    // 2 x 16KB, swizzled 256B rows

  const int tid  = threadIdx.x;
  const int lane = tid & 63;
  const int w    = tid >> 6;          // wave 0..3
  // XCD-bijective swizzle (512 % 8 == 0)
  const int lb   = (blockIdx.x & 7) * 64 + (blockIdx.x >> 3);
  const int m0   = (lb >> 1) * 16;
  const int nb0  = (lb & 1) * 64;

  f32x4 acc;
  acc[0] = 0.f; acc[1] = 0.f; acc[2] = 0.f; acc[3] = 0.f;

  float4 xs[2][2];   // 2 prefetch slots x 2 chunks (statically indexed under unroll)

  auto loadX = [&](float4* slot, int kt) {
#pragma unroll
    for (int i = 0; i < 2; ++i) {
      int c = tid + 256 * i;
      int row = c >> 5, kq = (c & 31) * 4;
      slot[i] = *reinterpret_cast<const float4*>(&X[(size_t)(m0 + row) * D_ + kt * 128 + kq]);
    }
  };
  auto writeX = [&](int buf, const float4* slot) {
#pragma unroll
    for (int i = 0; i < 2; ++i) {
      int c = tid + 256 * i;
      int row = c >> 5, kq = (c & 31) * 4;
      uint2 p;
      p.x = (unsigned int)f2bf(slot[i].x) | ((unsigned int)f2bf(slot[i].y) << 16);
      p.y = (unsigned int)f2bf(slot[i].z) | ((unsigned int)f2bf(slot[i].w) << 16);
      int byte_in_row = (kq * 2) ^ ((row & 7) << 4);
      *reinterpret_cast<uint2*>(reinterpret_cast<char*>(&sX[buf][0]) + row * 256 + byte_in_row) = p;
    }
  };
  auto issueP = [&](int buf, int kt) {
    const int k0 = kt * 128;
#pragma unroll
    for (int i = 0; i < 4; ++i) {
      int c = tid + 256 * i;
      int row = c >> 4, ch = c & 15;   // 16 chunks per 256B row
      gload_lds16(&PbT[(size_t)(nb0 + row) * D_ + k0 + ((ch ^ (row & 7)) * 8)],
                  reinterpret_cast<char*>(&sP[buf][0]) + c * 16);
    }
  };
  auto compute = [&](int buf) {
    const char* xb = reinterpret_cast<const char*>(&sX[buf][0]);
    const char* pb = reinterpret_cast<const char*>(&sP[buf][0]);
#pragma unroll
    for (int s = 0; s < 4; ++s) {
      int koffb = s * 64 + ((lane >> 4) << 4);
      int ar = lane & 15;
      short8 a = *reinterpret_cast<const short8*>(xb + ar * 256 + (koffb ^ ((ar & 7) << 4)));
      int br = w * 16 + (lane & 15);
      short8 b = *reinterpret_cast<const short8*>(pb + br * 256 + (koffb ^ ((br & 7) << 4)));
      acc = __builtin_amdgcn_mfma_f32_16x16x32_bf16(a, b, acc, 0, 0, 0);
    }
  };

  // prologue: issue X(0), P(0), X(1); write sX[0] (compiler counted-waits X(0) only)
  loadX(xs[0], 0);
  issueP(0, 0);
  loadX(xs[1], 1);
  writeX(0, xs[0]);
  // outstanding: P(0)x4, X(1)x2

#pragma unroll
  for (int kt = 0; kt < 8; ++kt) {
    const int buf = kt & 1;
    // retire P(kt) (4 oldest); keep X loads in flight; publish last iter's sX writes
    if (kt == 7) asm volatile("s_waitcnt vmcnt(0) lgkmcnt(0)" ::: "memory");
    else         asm volatile("s_waitcnt vmcnt(2) lgkmcnt(0)" ::: "memory");
    __builtin_amdgcn_sched_barrier(0);
    __builtin_amdgcn_s_barrier();
    compute(buf);
    // staging into buf^1: safe, all waves passed barrier@kt (readers of buf^1 done)
    if (kt < 7) issueP(buf ^ 1, kt + 1);
    if (kt < 6) loadX(xs[kt & 1], kt + 2);
    if (kt < 7) writeX(buf ^ 1, xs[(kt + 1) & 1]);
  }

  // epilogue: write bf16 t
  const int col = lane & 15;
#pragma unroll
  for (int q = 0; q < 4; ++q) {
    int row = ((lane >> 4) << 2) + q;
    Tb[(size_t)(m0 + row) * R_ + nb0 + w * 16 + col] = f2bf(acc[q]);
  }
}

// ---------------- K2: per-batch Gram + distance epilogue ----------------
// block = (b, i-tile it, j-quarter jq). grid=1024 -> 4 blocks/CU. (R7 verbatim.)
__global__ __launch_bounds__(256) void k2_gram(
    const unsigned short* __restrict__ Tb, float* __restrict__ Out) {
  __shared__ unsigned short sI[16 * 128];    // 4KB, swizzled 256B rows
  __shared__ unsigned short sJ[64 * 128];    // 16KB
  __shared__ float nI[16], nJ[64];

  const int tid  = threadIdx.x;
  const int lane = tid & 63;
  const int w    = tid >> 6;        // 0..3
  const int blk  = blockIdx.x;
  const int b    = blk >> 6;
  const int it   = (blk >> 2) & 15;
  const int jq   = blk & 3;

  // stage sI: 256 chunks of 16B (1/thread)
  {
    int row = tid >> 4, ch = tid & 15;
    gload_lds16(&Tb[(size_t)(b * L_ + it * 16 + row) * R_ + ((ch ^ (row & 7)) * 8)],
                reinterpret_cast<char*>(sI) + tid * 16);
  }
  // stage sJ: 1024 chunks (4/thread)
#pragma unroll
  for (int i = 0; i < 4; ++i) {
    int c = tid + 256 * i;
    int row = c >> 4, ch = c & 15;
    gload_lds16(&Tb[(size_t)(b * L_ + jq * 64 + row) * R_ + ((ch ^ (row & 7)) * 8)],
                reinterpret_cast<char*>(sJ) + c * 16);
  }
  __syncthreads();

  // norms: threads 0..159, row = t>>1 (0..15 -> sI, 16..79 -> sJ), half = t&1
  if (tid < 160) {
    int row = tid >> 1, h = tid & 1;
    const char* base = (row < 16) ? reinterpret_cast<const char*>(sI)
                                  : reinterpret_cast<const char*>(sJ);
    int r = (row < 16) ? row : row - 16;
    float s = 0.f;
#pragma unroll
    for (int j = 0; j < 8; ++j) {
      short8 v = *reinterpret_cast<const short8*>(base + r * 256 + ((h * 128 + j * 16) ^ ((r & 7) << 4)));
#pragma unroll
      for (int e = 0; e < 8; ++e) { float f = bf2f((unsigned short)v[e]); s += f * f; }
    }
    s += __shfl_xor(s, 1);
    if (h == 0) { if (row < 16) nI[row] = s; else nJ[row - 16] = s; }
  }

  // Gram via MFMA
  f32x4 acc;
  acc[0] = 0.f; acc[1] = 0.f; acc[2] = 0.f; acc[3] = 0.f;
  const char* ib = reinterpret_cast<const char*>(sI);
  const char* jb = reinterpret_cast<const char*>(sJ);
#pragma unroll
  for (int s = 0; s < 4; ++s) {
    int koffb = s * 64 + ((lane >> 4) << 4);
    int ar = lane & 15;
    short8 a = *reinterpret_cast<const short8*>(ib + ar * 256 + (koffb ^ ((ar & 7) << 4)));
    int br = w * 16 + (lane & 15);
    short8 bv = *reinterpret_cast<const short8*>(jb + br * 256 + (koffb ^ ((br & 7) << 4)));
    acc = __builtin_amdgcn_mfma_f32_16x16x32_bf16(a, bv, acc, 0, 0, 0);
  }
  __syncthreads();   // nI/nJ visible to all

  const int col = lane & 15;
  const int jj = w * 16 + col;
  const float nj = nJ[jj];
#pragma unroll
  for (int q = 0; q < 4; ++q) {
    int ir = ((lane >> 4) << 2) + q;
    float v = nI[ir] + nj - 2.0f * acc[q];
    Out[(size_t)(b * L_ + it * 16 + ir) * L_ + jq * 64 + jj] = fmaxf(v, 0.0f);
  }
}

extern "C" void kernel_launch(void* const* d_in, const int* in_sizes, int n_in,
                              void* d_out, int out_size, void* d_ws, size_t ws_size,
                              hipStream_t stream) {
  const float* X = (const float*)d_in[0];   // [16,256,1024]
  const float* P = (const float*)d_in[1];   // [1024,128]
  float* Out = (float*)d_out;               // [16,256,256]
  char* ws = (char*)d_ws;
  unsigned short* PbT = (unsigned short*)ws;                               // 256 KB
  unsigned short* Tb  = (unsigned short*)(ws + (size_t)R_ * D_ * 2);       // 1 MB

  k0_transpose_cast<<<128, 256, 0, stream>>>(P, PbT);
  k1_gemm<<<M_ / 16 * 2, 256, 0, stream>>>(X, PbT, Tb);
  k2_gram<<<B_ * 16 * 4, 256, 0, stream>>>(Tb, Out);
}